// Round 7
// baseline (177.011 us; speedup 1.0000x reference)
//
#include <hip/hip_runtime.h>

// Fused axial dual-branch attention, bf16 split-precision MFMA. One block per N.
// R14: RESTRUCTURE — kill the P^T LDS round-trip (R13 falsified the LDS-BW theory:
// -30% LDS traffic, -28% conflicts => +6% time; all pipes <40% => latency/barrier-bound).
// New decomposition: each wave owns t-chunk [32w,+32).
//   gram: A = ALL 128 s-rows of QP, B = wave's 2 t-tiles -> P with t on lid,
//   s on (quad,reg) == EXACTLY the PV A-frag layout (i=t=lid, k=s=quad*8+j),
//   because V's s-order is re-permuted in storage to match: tau(s) =
//   ((s>>2)&15)*8 + (s>>6)*4 + (s&3); PV reads VS[d][32ks+8q] as plain b128.
//   => P never touches LDS, zero cross-lane shuffle for the transpose.
// Softmax denominator is the only cross-wave data: 128 f32 via shfl_xor reduce +
// masked atomicAdd into TOT[s]; normalization folded into V (VS = V * rcp(TOT),
// 2048 muls vs 32768), P packed bf16 UNNORMALIZED right after exp2 (range 2^±17 ok).
// Barriers 11 -> 8; each branch's core is one barrier-free register stretch.
// LDS 29440 (5 blocks/CU); PT/PT-conflicts gone; A2 staged under PV1.
// Q GEMM 3-term hi/lo split; gram full-product 2-MFMA ([Qh;Ql]+[Ql;Qh])x[Qh;Ql].
// Frags (HW-verified): A[m=lane&15][k=quad*8+j]; B[k=quad*8+j][n=lane&15];
// D row=(lane>>4)*4+reg, col=lane&15.
// (R6 resubmit: 5th GPUAcquisitionTimeout; kernel unchanged — unmeasured kernels
//  get resubmitted, not edited. All paper audits done R3/R4.)
// Lessons: R5vsR8 occupancy>barriers; R6/R11 don't over-constrain allocator;
// R13: op-count cuts inside phases don't move latency-bound time.

typedef __attribute__((ext_vector_type(8))) short bh8;
typedef __attribute__((ext_vector_type(4))) float f32x4;
typedef unsigned short u16;
typedef unsigned int u32;

#define MFMA16(a,b,c) __builtin_amdgcn_mfma_f32_16x16x32_bf16(a,b,c,0,0,0)

#define AIMG_ST 72    // u16 (144 B rows)
#define QP_ST   40    // u16 (80 B rows)
#define VH_ST   136   // u16 (272 B rows)
#define VS_ST   136   // u16 (272 B rows), tau-permuted scaled V

#define OFF_AH   0        // 32x72x2 = 4608
#define OFF_AL   4608     // 4608
#define OFF_VIN  9216     // 4608 ; VS (16x136x2=4352) aliases here (disjoint lifetime)
#define OFF_QP   13824    // 128x40x2 = 10240
#define OFF_VH   24064    // 16x136x2 = 4352
#define LDS_BLOB 28416    // + sTOT 1024 = 29440 -> 5 blocks/CU (LDS-limited)

// ---- fast numeric helpers ----
__device__ __forceinline__ u32 cvtpk_rn(float f0, float f1) {
#if __has_builtin(__builtin_amdgcn_cvt_pk_bf16_f32)
    auto h = __builtin_amdgcn_cvt_pk_bf16_f32(f0, f1);
    u32 r; __builtin_memcpy(&r, &h, sizeof(r)); return r;
#else
    return ((__float_as_uint(f0) + 0x8000u) >> 16) |
           ((__float_as_uint(f1) + 0x8000u) & 0xFFFF0000u);
#endif
}
__device__ __forceinline__ float fexp2(float x) {
#if __has_builtin(__builtin_amdgcn_exp2f)
    return __builtin_amdgcn_exp2f(x);
#else
    return exp2f(x);
#endif
}
__device__ __forceinline__ float frcp(float x) {
#if __has_builtin(__builtin_amdgcn_rcpf)
    return __builtin_amdgcn_rcpf(x);
#else
    return 1.0f / x;
#endif
}
__device__ __forceinline__ void splitpk(float f0, float f1, u32& hp, u32& lp) {
    u32 u0 = __float_as_uint(f0), u1 = __float_as_uint(f1);
    hp = __builtin_amdgcn_perm(u1, u0, 0x07060302u);   // [u0.hi16 | u1.hi16]
    float r0 = f0 - __uint_as_float(u0 & 0xFFFF0000u);
    float r1 = f1 - __uint_as_float(u1 & 0xFFFF0000u);
    lp = cvtpk_rn(r0, r1);
}
__device__ __forceinline__ void split3(float f, u16& h, u16& l) {
    u32 u = __float_as_uint(f);
    u32 hf = u & 0xFFFF0000u;
    float r = f - __uint_as_float(hf);
    h = (u16)(hf >> 16);
    l = (u16)((__float_as_uint(r) + 0x8000u) >> 16);
}
__device__ __forceinline__ u16 rnbf(float f) {
    return (u16)((__float_as_uint(f) + 0x8000u) >> 16);
}
__device__ __forceinline__ float b2f(short v) {
    return __uint_as_float(((u32)(u16)v) << 16);
}
__device__ __forceinline__ float lrelu(float x) { return x > 0.f ? x : 0.2f * x; }
__device__ __forceinline__ bh8 mk8(u32 a, u32 b, u32 c, u32 d) {
    union { bh8 v; u32 u[4]; } x;
    x.u[0] = a; x.u[1] = b; x.u[2] = c; x.u[3] = d; return x.v;
}

// ws u16 layout: [WqH 4096][WqL 4096][WkH 4096][WkL 4096 (unused)]
// Wq pre-scaled by 0.5*sqrt(log2 e) so Gram is natively log2e-scaled for exp2.
__global__ void split_w_kernel(const float* __restrict__ Wq,
                               const float* __restrict__ Wk,
                               u16* __restrict__ ws)
{
    const int i = blockIdx.x * 256 + threadIdx.x;
    const int j = i & 4095;
    const float scale = (i < 4096) ? 0.6005612043932249f : 1.0f;
    const float f = ((i < 4096) ? Wq[j] : Wk[j]) * scale;
    const int base = (i < 4096) ? 0 : 8192;
    u16 h, l; split3(f, h, l);
    ws[base + j] = h;
    ws[base + 4096 + j] = l;
}

#define WOFF(n, ks) (((n)*16 + lid)*64 + (ks)*32 + quad*8)

// Q GEMM: 3-term hi/lo split, 12 MFMA, -> QP (hi cols [0,16), lo cols [16,32)).
__device__ __forceinline__ void gemm_q(const u16* Ah, const u16* Al,
                                       const u16* wsu,
                                       u16* qp, int miQ, int niA, int lid, int quad)
{
    const bh8 h0a = *(const bh8*)(wsu +        WOFF(niA+0,0));
    const bh8 h0b = *(const bh8*)(wsu +        WOFF(niA+0,1));
    const bh8 h1a = *(const bh8*)(wsu +        WOFF(niA+1,0));
    const bh8 h1b = *(const bh8*)(wsu +        WOFF(niA+1,1));
    const bh8 l0a = *(const bh8*)(wsu + 4096 + WOFF(niA+0,0));
    const bh8 l0b = *(const bh8*)(wsu + 4096 + WOFF(niA+0,1));
    const bh8 l1a = *(const bh8*)(wsu + 4096 + WOFF(niA+1,0));
    const bh8 l1b = *(const bh8*)(wsu + 4096 + WOFF(niA+1,1));
    const int offA = (miQ*16 + lid)*AIMG_ST + quad*8;
    bh8 ah0 = *(const bh8*)(Ah + offA);
    bh8 ah1 = *(const bh8*)(Ah + offA + 32);
    bh8 al0 = *(const bh8*)(Al + offA);
    bh8 al1 = *(const bh8*)(Al + offA + 32);
    f32x4 acc0 = {0.f,0.f,0.f,0.f}, acc1 = {0.f,0.f,0.f,0.f};
    acc0 = MFMA16(ah0, h0a, acc0); acc0 = MFMA16(ah0, l0a, acc0); acc0 = MFMA16(al0, h0a, acc0);
    acc0 = MFMA16(ah1, h0b, acc0); acc0 = MFMA16(ah1, l0b, acc0); acc0 = MFMA16(al1, h0b, acc0);
    acc1 = MFMA16(ah0, h1a, acc1); acc1 = MFMA16(ah0, l1a, acc1); acc1 = MFMA16(al0, h1a, acc1);
    acc1 = MFMA16(ah1, h1b, acc1); acc1 = MFMA16(ah1, l1b, acc1); acc1 = MFMA16(al1, h1b, acc1);
    const int d0 = miQ*8 + quad*2;
    const int rA = (niA+0)*16 + lid;
    const int rB = (niA+1)*16 + lid;
    u32 h, l;
    splitpk(acc0[0], acc0[2], h, l);
    *(u32*)(qp + rA*QP_ST + d0)       = h;  *(u32*)(qp + rA*QP_ST + 16 + d0)       = l;
    splitpk(acc0[1], acc0[3], h, l);
    *(u32*)(qp + (64+rA)*QP_ST + d0)  = h;  *(u32*)(qp + (64+rA)*QP_ST + 16 + d0)  = l;
    splitpk(acc1[0], acc1[2], h, l);
    *(u32*)(qp + rB*QP_ST + d0)       = h;  *(u32*)(qp + rB*QP_ST + 16 + d0)       = l;
    splitpk(acc1[1], acc1[3], h, l);
    *(u32*)(qp + (64+rB)*QP_ST + d0)  = h;  *(u32*)(qp + (64+rB)*QP_ST + 16 + d0)  = l;
}

// V GEMM: single-term bf16, 4 MFMA, writes VH[d][s] (s-linear).
__device__ __forceinline__ void gemm_v(const u16* Vin, const u16* wsu,
                                       u16* vh, int miQ, int niA, int lid, int quad)
{
    const bh8 h0a = *(const bh8*)(wsu + 8192 + WOFF(niA+0,0));
    const bh8 h0b = *(const bh8*)(wsu + 8192 + WOFF(niA+0,1));
    const bh8 h1a = *(const bh8*)(wsu + 8192 + WOFF(niA+1,0));
    const bh8 h1b = *(const bh8*)(wsu + 8192 + WOFF(niA+1,1));
    const int offA = (miQ*16 + lid)*AIMG_ST + quad*8;
    bh8 ah0 = *(const bh8*)(Vin + offA);
    bh8 ah1 = *(const bh8*)(Vin + offA + 32);
    f32x4 acc0 = {0.f,0.f,0.f,0.f}, acc1 = {0.f,0.f,0.f,0.f};
    acc0 = MFMA16(ah0, h0a, acc0); acc0 = MFMA16(ah1, h0b, acc0);
    acc1 = MFMA16(ah0, h1a, acc1); acc1 = MFMA16(ah1, h1b, acc1);
    #pragma unroll
    for (int r = 0; r < 4; ++r) {
        const int l = miQ*16 + quad*4 + r;
        const int d = l >> 1;
        const int sbase = (l & 1) << 6;
        vh[d*VH_ST + sbase + (niA + 0)*16 + lid] = rnbf(acc0[r]);
        vh[d*VH_ST + sbase + (niA + 1)*16 + lid] = rnbf(acc1[r]);
    }
}

// Gram for wave's t-chunk [32w,+32) vs ALL 128 s. P kept in registers (packed
// bf16, unnormalized): pk[mt][nt][rp] covers (s=16mt+4quad+{2rp,2rp+1},
// t=32w+16nt+lid). Denominator partials (sum over this wave's 32 t) reduced
// over lid via shfl_xor, deposited by lane lid==mt via atomicAdd into TOT[s].
__device__ __forceinline__ void gram_branch(const u16* Qp, float* TOT,
                                            u32 pk[8][2][2], int w, int lid, int quad)
{
    const bh8 b0 = *(const bh8*)(Qp + (32*w +      lid)*QP_ST + quad*8);   // [Qh;Ql]
    const bh8 b1 = *(const bh8*)(Qp + (32*w + 16 + lid)*QP_ST + quad*8);
    #pragma unroll
    for (int mt = 0; mt < 8; ++mt) {
        const u16* arow = Qp + (16*mt + lid)*QP_ST;
        const bh8 a_hl = *(const bh8*)(arow + quad*8);               // [Qh;Ql]
        const bh8 a_lh = *(const bh8*)(arow + ((quad+2)&3)*8);       // [Ql;Qh]
        f32x4 g0 = {0.f,0.f,0.f,0.f}, g1 = {0.f,0.f,0.f,0.f};
        g0 = MFMA16(a_hl, b0, g0); g0 = MFMA16(a_lh, b0, g0);        // full product
        g1 = MFMA16(a_hl, b1, g1); g1 = MFMA16(a_lh, b1, g1);
        const float p00 = fexp2(g0[0]), p01 = fexp2(g0[1]);
        const float p02 = fexp2(g0[2]), p03 = fexp2(g0[3]);
        const float p10 = fexp2(g1[0]), p11 = fexp2(g1[1]);
        const float p12 = fexp2(g1[2]), p13 = fexp2(g1[3]);
        pk[mt][0][0] = cvtpk_rn(p00, p01); pk[mt][0][1] = cvtpk_rn(p02, p03);
        pk[mt][1][0] = cvtpk_rn(p10, p11); pk[mt][1][1] = cvtpk_rn(p12, p13);
        float s0 = p00 + p10, s1 = p01 + p11, s2 = p02 + p12, s3 = p03 + p13;
        s0 += __shfl_xor(s0,1); s0 += __shfl_xor(s0,2); s0 += __shfl_xor(s0,4); s0 += __shfl_xor(s0,8);
        s1 += __shfl_xor(s1,1); s1 += __shfl_xor(s1,2); s1 += __shfl_xor(s1,4); s1 += __shfl_xor(s1,8);
        s2 += __shfl_xor(s2,1); s2 += __shfl_xor(s2,2); s2 += __shfl_xor(s2,4); s2 += __shfl_xor(s2,8);
        s3 += __shfl_xor(s3,1); s3 += __shfl_xor(s3,2); s3 += __shfl_xor(s3,4); s3 += __shfl_xor(s3,8);
        if (lid == mt) {
            atomicAdd(&TOT[16*mt + 4*quad + 0], s0);
            atomicAdd(&TOT[16*mt + 4*quad + 1], s1);
            atomicAdd(&TOT[16*mt + 4*quad + 2], s2);
            atomicAdd(&TOT[16*mt + 4*quad + 3], s3);
        }
    }
}

// VS[d][tau(s)] = V[d][s] * rcp(TOT[s]); tau(s) = ((s>>2)&15)*8 + (s>>6)*4 + (s&3).
// Wave w handles s in [32w,+32): thread (quad,lid): d=lid, s = 32w+8quad+{0..7}.
__device__ __forceinline__ void scale_v(const u16* Vh, u16* VS, const float* TOT,
                                        int w, int lid, int quad)
{
    const int s0 = 32*w + 8*quad;
    const float4 t0 = *(const float4*)(TOT + s0);
    const float4 t1 = *(const float4*)(TOT + s0 + 4);
    const bh8 vr = *(const bh8*)(Vh + lid*VH_ST + s0);
    const u32 w0 = cvtpk_rn(b2f(vr[0])*frcp(t0.x), b2f(vr[1])*frcp(t0.y));
    const u32 w1 = cvtpk_rn(b2f(vr[2])*frcp(t0.z), b2f(vr[3])*frcp(t0.w));
    const u32 w2 = cvtpk_rn(b2f(vr[4])*frcp(t1.x), b2f(vr[5])*frcp(t1.y));
    const u32 w3 = cvtpk_rn(b2f(vr[6])*frcp(t1.z), b2f(vr[7])*frcp(t1.w));
    const int tb = ((8*w + 2*quad) & 15)*8 + (w >> 1)*4;   // tau of j=0..3; j=4..7 at +8
    *(uint2*)(VS + lid*VS_ST + tb)     = make_uint2(w0, w1);
    *(uint2*)(VS + lid*VS_ST + tb + 8) = make_uint2(w2, w3);
}

// PV: D[t][d] over K=128 (4 ks steps of 32 s). A-frag = pure register remap of pk;
// B-frag = b128 from tau-permuted VS (s-order matches pk by construction).
__device__ __forceinline__ void pv_branch(const u16* VS, const u32 pk[8][2][2],
                                          f32x4& c0, f32x4& c1, int lid, int quad)
{
    #pragma unroll
    for (int ks = 0; ks < 4; ++ks) {
        const bh8 vb = *(const bh8*)(VS + lid*VS_ST + 32*ks + 8*quad);
        const bh8 a0 = mk8(pk[ks][0][0], pk[ks][0][1], pk[ks+4][0][0], pk[ks+4][0][1]);
        const bh8 a1 = mk8(pk[ks][1][0], pk[ks][1][1], pk[ks+4][1][0], pk[ks+4][1][1]);
        c0 = MFMA16(a0, vb, c0);
        c1 = MFMA16(a1, vb, c1);
    }
}

__global__ __launch_bounds__(256, 4)
void axial_attn_mfma(const float* __restrict__ z, const u16* __restrict__ wsu,
                     float* __restrict__ out)
{
    __shared__ __align__(16) unsigned char lds[LDS_BLOB];
    __shared__ __align__(16) float sTOT[2][128];
    u16* const ptAh = (u16*)(lds + OFF_AH);
    u16* const ptAl = (u16*)(lds + OFF_AL);
    u16* const ptVI = (u16*)(lds + OFF_VIN);
    u16* const ptVS = (u16*)(lds + OFF_VIN);   // aliases VIN (disjoint lifetime)
    u16* const ptQP = (u16*)(lds + OFF_QP);
    u16* const ptVH = (u16*)(lds + OFF_VH);

    const int tid = threadIdx.x;
    const int w = tid >> 6, lane = tid & 63, quad = lane >> 4, lid = lane & 15;

    // XCD-aware swizzle: same-XCD blocks cover contiguous xi
    const int blk = blockIdx.x;
    const int j   = blk >> 3;
    const int xi  = ((blk & 7) << 4) | (j & 15);
    const int q   = (j >> 4) & 3;
    const int bi  = j >> 6;
    const int N   = (((bi << 7) | xi) << 2) | q;
    const size_t zbase = (size_t)bi << 20;

    const int c8 = tid >> 5, l5 = tid & 31;        // ch-octet, A-row
    const int vl0 = tid >> 4, vc0 = (tid & 15) << 2;
    const int miQ = w >> 1, niA = (w & 1) * 2;

    // ---- register prefetch of ALL z reads ----
    float a1r[8], a2r[8];
    float4 v4[2];
    {
        const float* s1 = z + zbase + ((size_t)xi << 7) + (q << 5) + l5;
        const float* s2 = z + zbase + (((size_t)(q*32 + l5)) << 7) + xi;
        #pragma unroll
        for (int k = 0; k < 8; ++k)
            a1r[k] = s1[(size_t)(c8*8 + k) << 14];
        const float4* sv = (const float4*)(z + ((size_t)N << 11));
        v4[0] = sv[tid]; v4[1] = sv[tid + 256];
        #pragma unroll
        for (int k = 0; k < 8; ++k)
            a2r[k] = s2[(size_t)(c8*8 + k) << 14];
    }

    // ---- zero denominators + stage A1 (hi/lo b128) + Vin (RN pair-pack) ----
    ((float*)sTOT)[tid] = 0.f;   // 2*128 = 256 floats, one per thread
    {
        u32 hp[4], lp[4];
        #pragma unroll
        for (int k = 0; k < 4; ++k) splitpk(a1r[2*k], a1r[2*k+1], hp[k], lp[k]);
        *(uint4*)(ptAh + l5*AIMG_ST + c8*8) = make_uint4(hp[0], hp[1], hp[2], hp[3]);
        *(uint4*)(ptAl + l5*AIMG_ST + c8*8) = make_uint4(lp[0], lp[1], lp[2], lp[3]);
    }
    #pragma unroll
    for (int k = 0; k < 2; ++k) {
        const float4 vv = v4[k];
        uint2 dv;
        dv.x = cvtpk_rn(vv.x, vv.y);
        dv.y = cvtpk_rn(vv.z, vv.w);
        *(uint2*)(ptVI + (vl0 + 16*k)*AIMG_ST + vc0) = dv;
    }
    __syncthreads();                                            // S1

    gemm_q(ptAh, ptAl, wsu, ptQP, miQ, niA, lid, quad);         // Q1
    gemm_v(ptVI, wsu, ptVH, miQ, niA, lid, quad);               // V (VIN dead after)
    __syncthreads();                                            // S2

    // ---- branch 1: gram (reg P) + denom -> scale V -> PV ----
    u32 pk1[8][2][2];
    gram_branch(ptQP, &sTOT[0][0], pk1, w, lid, quad);
    __syncthreads();                                            // S3 (TOT[0] complete)
    scale_v(ptVH, ptVS, &sTOT[0][0], w, lid, quad);
    __syncthreads();                                            // S4 (VS ready)

    // stage A2 early (AhAl free since S2); overlaps with PV1
    {
        u32 hp[4], lp[4];
        #pragma unroll
        for (int k = 0; k < 4; ++k) splitpk(a2r[2*k], a2r[2*k+1], hp[k], lp[k]);
        *(uint4*)(ptAh + l5*AIMG_ST + c8*8) = make_uint4(hp[0], hp[1], hp[2], hp[3]);
        *(uint4*)(ptAl + l5*AIMG_ST + c8*8) = make_uint4(lp[0], lp[1], lp[2], lp[3]);
    }
    f32x4 c10 = {0.f,0.f,0.f,0.f}, c11 = {0.f,0.f,0.f,0.f};
    pv_branch(ptVS, pk1, c10, c11, lid, quad);
    __syncthreads();                                            // S5 (A2 staged; VS reads done)

    gemm_q(ptAh, ptAl, wsu, ptQP, miQ, niA, lid, quad);         // Q2
    __syncthreads();                                            // S6

    // ---- branch 2 ----
    u32 pk2[8][2][2];
    gram_branch(ptQP, &sTOT[1][0], pk2, w, lid, quad);
    __syncthreads();                                            // S7 (TOT[1] complete)
    scale_v(ptVH, ptVS, &sTOT[1][0], w, lid, quad);
    __syncthreads();                                            // S8 (VS ready)
    f32x4 c20 = {0.f,0.f,0.f,0.f}, c21 = {0.f,0.f,0.f,0.f};
    pv_branch(ptVS, pk2, c20, c21, lid, quad);

    // ---- epilogue: out[d=lid][t] = lrelu(ctx1)+lrelu(ctx2), float4 over r ----
    float* ob = out + ((size_t)N << 11) + lid*128;
    #pragma unroll
    for (int tj2 = 0; tj2 < 2; ++tj2) {
        f32x4 a = tj2 ? c11 : c10;
        f32x4 b = tj2 ? c21 : c20;
        float4 ov;
        ov.x = lrelu(a[0]) + lrelu(b[0]);
        ov.y = lrelu(a[1]) + lrelu(b[1]);
        ov.z = lrelu(a[2]) + lrelu(b[2]);
        ov.w = lrelu(a[3]) + lrelu(b[3]);
        *(float4*)(ob + (2*w + tj2)*16 + quad*4) = ov;
    }
}

extern "C" void kernel_launch(void* const* d_in, const int* in_sizes, int n_in,
                              void* d_out, int out_size, void* d_ws, size_t ws_size,
                              hipStream_t stream) {
    const float* z  = (const float*)d_in[0];
    const float* Wq = (const float*)d_in[1];
    const float* Wk = (const float*)d_in[2];
    float* out = (float*)d_out;
    u16* ws = (u16*)d_ws;
    hipLaunchKernelGGL(split_w_kernel, dim3(32), dim3(256), 0, stream, Wq, Wk, ws);
    hipLaunchKernelGGL(axial_attn_mfma, dim3(4096), dim3(256), 0, stream, z, ws, out);
}

// Round 9
// 154.529 us; speedup vs baseline: 1.1455x; 1.1455x over previous
//
#include <hip/hip_runtime.h>

// Fused axial dual-branch attention, bf16 split-precision MFMA. One block per N.
// R15 = REVERT to R12 (best measured: 93 µs hot dispatch / 154.9 bench) + the one
// mechanically-pure R13 item: pv_ctx V-frag hoist (CSE, at worst codegen-identical).
// WHY: R13 (-30% LDS reads) = +6%; R14 (P-in-reg, 8 barriers) = +27%. Across all
// three, MfmaUtil x time = const (1163/1163/1150) -> MFMA work fixed, TIME set by
// per-phase serial latency chains. R14's __shfl_xor = ds_swizzle (LDS-pipe!): 256
// shuffles/thread in 4-chains behind exp2 replaced ~24 PT ops -> longer chain.
// Falsified: LDS-BW theory (R13), barrier-count theory (R14), P-in-reg (R14).
// (R8 resubmit: GPUAcquisitionTimeout — no data; kernel unchanged.)
// PT: 128 t x 64 s, stride 64 u16; 8B units swizzled u' = u ^ (2*(t&7)).
// Wave w: gram s-tile [64h+16w,+16) -> PT half; PV t-chunk [32w,+32), K=64/half.
// Q GEMM 3-term hi/lo split; V single-term bf16; exp2 softmax, scale in Wq.
// Frags (HW-verified): A[m=lane&15][k=quad*8+j]; B[k=quad*8+j][n=lane&15];
// D row=(lane>>4)*4+reg, col=lane&15.
// Lessons: R5vsR8 occupancy>barriers; R6/R11 don't over-constrain allocator;
// R13 op-count cuts don't move latency-bound time; R14 shuffles ARE LDS ops.

typedef __attribute__((ext_vector_type(8))) short bh8;
typedef __attribute__((ext_vector_type(4))) float f32x4;
typedef unsigned short u16;
typedef unsigned int u32;

#define MFMA16(a,b,c) __builtin_amdgcn_mfma_f32_16x16x32_bf16(a,b,c,0,0,0)

#define AIMG_ST 72    // u16 (144 B rows)
#define QP_ST   40    // u16 (80 B rows)
#define VH_ST   136   // u16 (272 B rows)
#define PT_ST   64    // u16 (128 B rows, XOR-swizzled 8B units, no pad)

#define OFF_AH   0
#define OFF_AL   4608
#define OFF_VIN  9216
#define OFF_PT   0        // PT (128x64x2=16384) aliases Ah/Al/VIN (disjoint lifetimes)
#define OFF_QP   16384    // 128x40x2 = 10240
#define OFF_VH   26624    // 16x136x2 = 4352
#define LDS_TOT  30976    // x5 blocks = 151.25 KB <= 160 KB -> 5 blocks/CU (LDS-limited)

// ---- fast numeric helpers (guarded HW builtins, safe fallbacks) ----
__device__ __forceinline__ u32 cvtpk_rn(float f0, float f1) {
#if __has_builtin(__builtin_amdgcn_cvt_pk_bf16_f32)
    auto h = __builtin_amdgcn_cvt_pk_bf16_f32(f0, f1);
    u32 r; __builtin_memcpy(&r, &h, sizeof(r)); return r;
#else
    return ((__float_as_uint(f0) + 0x8000u) >> 16) |
           ((__float_as_uint(f1) + 0x8000u) & 0xFFFF0000u);
#endif
}
__device__ __forceinline__ float fexp2(float x) {
#if __has_builtin(__builtin_amdgcn_exp2f)
    return __builtin_amdgcn_exp2f(x);
#else
    return exp2f(x);
#endif
}
__device__ __forceinline__ float frcp(float x) {
#if __has_builtin(__builtin_amdgcn_rcpf)
    return __builtin_amdgcn_rcpf(x);
#else
    return 1.0f / x;
#endif
}
// hi = trunc-bf16 pair (1 v_perm), lo = RN-bf16(residual) pair
__device__ __forceinline__ void splitpk(float f0, float f1, u32& hp, u32& lp) {
    u32 u0 = __float_as_uint(f0), u1 = __float_as_uint(f1);
    hp = __builtin_amdgcn_perm(u1, u0, 0x07060302u);   // [u0.hi16 | u1.hi16]
    float r0 = f0 - __uint_as_float(u0 & 0xFFFF0000u);
    float r1 = f1 - __uint_as_float(u1 & 0xFFFF0000u);
    lp = cvtpk_rn(r0, r1);
}
__device__ __forceinline__ void split3(float f, u16& h, u16& l) {
    u32 u = __float_as_uint(f);
    u32 hf = u & 0xFFFF0000u;
    float r = f - __uint_as_float(hf);
    h = (u16)(hf >> 16);
    l = (u16)((__float_as_uint(r) + 0x8000u) >> 16);
}
__device__ __forceinline__ u16 rnbf(float f) {
    return (u16)((__float_as_uint(f) + 0x8000u) >> 16);
}
__device__ __forceinline__ float lrelu(float x) { return x > 0.f ? x : 0.2f * x; }

// ws u16 layout: [WqH 4096][WqL 4096][WkH 4096][WkL 4096 (unused)]
// Wq pre-scaled by 0.5*sqrt(log2 e) so Gram is natively log2e-scaled for exp2.
__global__ void split_w_kernel(const float* __restrict__ Wq,
                               const float* __restrict__ Wk,
                               u16* __restrict__ ws)
{
    const int i = blockIdx.x * 256 + threadIdx.x;
    const int j = i & 4095;
    const float scale = (i < 4096) ? 0.6005612043932249f : 1.0f;
    const float f = ((i < 4096) ? Wq[j] : Wk[j]) * scale;
    const int base = (i < 4096) ? 0 : 8192;
    u16 h, l; split3(f, h, l);
    ws[base + j] = h;
    ws[base + 4096 + j] = l;
}

#define WOFF(n, ks) (((n)*16 + lid)*64 + (ks)*32 + quad*8)

// Q GEMM: 3-term hi/lo split, 12 MFMA (scale pre-folded into weights), -> Qpack.
__device__ __forceinline__ void gemm_q(const u16* Ah, const u16* Al,
                                       const u16* wsu,
                                       u16* qp, int miQ, int niA, int lid, int quad)
{
    const bh8 h0a = *(const bh8*)(wsu +        WOFF(niA+0,0));
    const bh8 h0b = *(const bh8*)(wsu +        WOFF(niA+0,1));
    const bh8 h1a = *(const bh8*)(wsu +        WOFF(niA+1,0));
    const bh8 h1b = *(const bh8*)(wsu +        WOFF(niA+1,1));
    const bh8 l0a = *(const bh8*)(wsu + 4096 + WOFF(niA+0,0));
    const bh8 l0b = *(const bh8*)(wsu + 4096 + WOFF(niA+0,1));
    const bh8 l1a = *(const bh8*)(wsu + 4096 + WOFF(niA+1,0));
    const bh8 l1b = *(const bh8*)(wsu + 4096 + WOFF(niA+1,1));
    const int offA = (miQ*16 + lid)*AIMG_ST + quad*8;
    bh8 ah0 = *(const bh8*)(Ah + offA);
    bh8 ah1 = *(const bh8*)(Ah + offA + 32);
    bh8 al0 = *(const bh8*)(Al + offA);
    bh8 al1 = *(const bh8*)(Al + offA + 32);
    f32x4 acc0 = {0.f,0.f,0.f,0.f}, acc1 = {0.f,0.f,0.f,0.f};
    acc0 = MFMA16(ah0, h0a, acc0); acc0 = MFMA16(ah0, l0a, acc0); acc0 = MFMA16(al0, h0a, acc0);
    acc0 = MFMA16(ah1, h0b, acc0); acc0 = MFMA16(ah1, l0b, acc0); acc0 = MFMA16(al1, h0b, acc0);
    acc1 = MFMA16(ah0, h1a, acc1); acc1 = MFMA16(ah0, l1a, acc1); acc1 = MFMA16(al0, h1a, acc1);
    acc1 = MFMA16(ah1, h1b, acc1); acc1 = MFMA16(ah1, l1b, acc1); acc1 = MFMA16(al1, h1b, acc1);
    #pragma unroll
    for (int r = 0; r < 4; ++r) {
        const int l = miQ*16 + quad*4 + r;
        const int d = l >> 1;
        const int sbase = (l & 1) << 6;
        const int s0 = sbase + (niA + 0)*16 + lid;
        const int s1 = sbase + (niA + 1)*16 + lid;
        u32 hp, lp;
        splitpk(acc0[r], acc1[r], hp, lp);
        qp[s0*QP_ST + d]      = (u16)hp;
        qp[s0*QP_ST + 16 + d] = (u16)lp;
        qp[s1*QP_ST + d]      = (u16)(hp >> 16);
        qp[s1*QP_ST + 16 + d] = (u16)(lp >> 16);
    }
}

// V GEMM: single-term bf16, 4 MFMA, writes VH[d][s].
__device__ __forceinline__ void gemm_v(const u16* Vin, const u16* wsu,
                                       u16* vh, int miQ, int niA, int lid, int quad)
{
    const bh8 h0a = *(const bh8*)(wsu + 8192 + WOFF(niA+0,0));
    const bh8 h0b = *(const bh8*)(wsu + 8192 + WOFF(niA+0,1));
    const bh8 h1a = *(const bh8*)(wsu + 8192 + WOFF(niA+1,0));
    const bh8 h1b = *(const bh8*)(wsu + 8192 + WOFF(niA+1,1));
    const int offA = (miQ*16 + lid)*AIMG_ST + quad*8;
    bh8 ah0 = *(const bh8*)(Vin + offA);
    bh8 ah1 = *(const bh8*)(Vin + offA + 32);
    f32x4 acc0 = {0.f,0.f,0.f,0.f}, acc1 = {0.f,0.f,0.f,0.f};
    acc0 = MFMA16(ah0, h0a, acc0); acc0 = MFMA16(ah1, h0b, acc0);
    acc1 = MFMA16(ah0, h1a, acc1); acc1 = MFMA16(ah1, h1b, acc1);
    #pragma unroll
    for (int r = 0; r < 4; ++r) {
        const int l = miQ*16 + quad*4 + r;
        const int d = l >> 1;
        const int sbase = (l & 1) << 6;
        vh[d*VH_ST + sbase + (niA + 0)*16 + lid] = rnbf(acc0[r]);
        vh[d*VH_ST + sbase + (niA + 1)*16 + lid] = rnbf(acc1[r]);
    }
}

// Gram + wave-local softmax (exp2, scale pre-folded) for s-tile [64h+16w, +16).
// P^T write: one 8B unit per (lane,ti), unit index (4w+quad) ^ (2*(t&7)), t&7==lid&7.
__device__ __forceinline__ void gram_pt(const u16* Qp, u16* PT, int h,
                                        int w, int lid, int quad)
{
    const u16* arow = Qp + (h*64 + 16*w + lid)*QP_ST;
    bh8 a1 = *(const bh8*)(arow + quad*8);                        // [Qh;Ql]
    bh8 t  = *(const bh8*)(arow + ((quad >= 2) ? (quad-2)*8 : 0));
    bh8 zz = t ^ t;
    bh8 a2 = (quad < 2) ? zz : t;                                 // [0;Qh]
    f32x4 g[8];
    #pragma unroll
    for (int ti = 0; ti < 8; ++ti) {
        const u16* brow = Qp + (ti*16 + lid)*QP_ST;
        bh8 b1 = *(const bh8*)(brow + (quad & 1)*8);              // [Qh;Qh]
        bh8 b2 = *(const bh8*)(brow + quad*8);                    // [Qh;Ql]
        f32x4 acc = {0.f,0.f,0.f,0.f};
        acc = MFMA16(a1, b1, acc);
        acc = MFMA16(a2, b2, acc);
        g[ti] = acc;
    }
    float inv[4];
    #pragma unroll
    for (int r = 0; r < 4; ++r) {
        float s = 0.f;
        #pragma unroll
        for (int ti = 0; ti < 8; ++ti) {
            const float p = fexp2(g[ti][r]);
            g[ti][r] = p; s += p;
        }
        s += __shfl_xor(s, 1); s += __shfl_xor(s, 2);
        s += __shfl_xor(s, 4); s += __shfl_xor(s, 8);
        inv[r] = frcp(s);
    }
    const int X  = 2*(lid & 7);               // row-dependent unit swizzle
    const int uc = ((4*w + quad) ^ X) << 2;   // u16 offset of this lane's 8B unit
    #pragma unroll
    for (int ti = 0; ti < 8; ++ti) {
        uint2 dv;
        dv.x = cvtpk_rn(g[ti][0]*inv[0], g[ti][1]*inv[1]);
        dv.y = cvtpk_rn(g[ti][2]*inv[2], g[ti][3]*inv[3]);
        *(uint2*)(PT + (ti*16 + lid)*PT_ST + uc) = dv;
    }
}

// PV for t-chunk [32w,+32), K=64 (s-half h), accumulating into c0,c1.
// V fragments hoisted out of the tj2 loop (same address both iterations; CSE-safe).
// P^T read: 16B = unit pair {(8ks+2quad)^X, +1} (X even -> adjacent & aligned).
__device__ __forceinline__ void pv_ctx(const u16* PT, const u16* Vh, int h,
                                       f32x4& c0, f32x4& c1, int w, int lid, int quad)
{
    const int X = 2*(lid & 7);
    const bh8 vb0 = *(const bh8*)(Vh + lid*VH_ST + h*64 +      quad*8);
    const bh8 vb1 = *(const bh8*)(Vh + lid*VH_ST + h*64 + 32 + quad*8);
    #pragma unroll
    for (int tj2 = 0; tj2 < 2; ++tj2) {
        const int tj = 2*w + tj2;
        const bh8 pa0 = *(const bh8*)(PT + (tj*16 + lid)*PT_ST + (((    2*quad) ^ X) << 2));
        const bh8 pa1 = *(const bh8*)(PT + (tj*16 + lid)*PT_ST + (((8 + 2*quad) ^ X) << 2));
        f32x4 acc = tj2 ? c1 : c0;
        acc = MFMA16(pa0, vb0, acc);
        acc = MFMA16(pa1, vb1, acc);
        if (tj2) c1 = acc; else c0 = acc;
    }
}

__global__ __launch_bounds__(256, 4)
void axial_attn_mfma(const float* __restrict__ z, const u16* __restrict__ wsu,
                     float* __restrict__ out)
{
    __shared__ __align__(16) unsigned char lds[LDS_TOT];
    u16* const ptAh = (u16*)(lds + OFF_AH);
    u16* const ptAl = (u16*)(lds + OFF_AL);
    u16* const ptPT = (u16*)(lds + OFF_PT);
    u16* const ptVI = (u16*)(lds + OFF_VIN);
    u16* const ptQP = (u16*)(lds + OFF_QP);
    u16* const ptVH = (u16*)(lds + OFF_VH);

    const int tid = threadIdx.x;
    const int w = tid >> 6, lane = tid & 63, quad = lane >> 4, lid = lane & 15;

    // XCD-aware swizzle: same-XCD blocks cover contiguous xi
    const int blk = blockIdx.x;
    const int j   = blk >> 3;
    const int xi  = ((blk & 7) << 4) | (j & 15);
    const int q   = (j >> 4) & 3;
    const int bi  = j >> 6;
    const int N   = (((bi << 7) | xi) << 2) | q;
    const size_t zbase = (size_t)bi << 20;

    const int c8 = tid >> 5, l5 = tid & 31;        // ch-octet, A-row
    const int vl0 = tid >> 4, vc0 = (tid & 15) << 2;
    const int miQ = w >> 1, niA = (w & 1) * 2;

    // ---- register prefetch of ALL z reads (thread owns 8 consecutive ch) ----
    float a1r[8], a2r[8];
    float4 v4[2];
    {
        const float* s1 = z + zbase + ((size_t)xi << 7) + (q << 5) + l5;
        const float* s2 = z + zbase + (((size_t)(q*32 + l5)) << 7) + xi;
        #pragma unroll
        for (int k = 0; k < 8; ++k)
            a1r[k] = s1[(size_t)(c8*8 + k) << 14];
        const float4* sv = (const float4*)(z + ((size_t)N << 11));
        v4[0] = sv[tid]; v4[1] = sv[tid + 256];
        #pragma unroll
        for (int k = 0; k < 8; ++k)
            a2r[k] = s2[(size_t)(c8*8 + k) << 14];
    }

    // ---- stage A1 (hi/lo, single b128 each) + Vin (RN pair-pack) ----
    {
        u32 hp[4], lp[4];
        #pragma unroll
        for (int k = 0; k < 4; ++k) splitpk(a1r[2*k], a1r[2*k+1], hp[k], lp[k]);
        *(uint4*)(ptAh + l5*AIMG_ST + c8*8) = make_uint4(hp[0], hp[1], hp[2], hp[3]);
        *(uint4*)(ptAl + l5*AIMG_ST + c8*8) = make_uint4(lp[0], lp[1], lp[2], lp[3]);
    }
    #pragma unroll
    for (int k = 0; k < 2; ++k) {
        const float4 vv = v4[k];
        uint2 dv;
        dv.x = cvtpk_rn(vv.x, vv.y);
        dv.y = cvtpk_rn(vv.z, vv.w);
        *(uint2*)(ptVI + (vl0 + 16*k)*AIMG_ST + vc0) = dv;
    }
    __syncthreads();                                            // S1

    gemm_q(ptAh, ptAl, wsu, ptQP, miQ, niA, lid, quad);         // Q1
    gemm_v(ptVI, wsu, ptVH, miQ, niA, lid, quad);               // V
    __syncthreads();                                            // S2

    f32x4 c10 = {0.f,0.f,0.f,0.f}, c11 = {0.f,0.f,0.f,0.f};
    gram_pt(ptQP, ptPT, 0, w, lid, quad);                       // branch-1 s-half 0
    __syncthreads();                                            // S3
    pv_ctx(ptPT, ptVH, 0, c10, c11, w, lid, quad);
    __syncthreads();                                            // S4 (WAR on PT)
    gram_pt(ptQP, ptPT, 1, w, lid, quad);                       // branch-1 s-half 1
    __syncthreads();                                            // S5
    pv_ctx(ptPT, ptVH, 1, c10, c11, w, lid, quad);
    __syncthreads();                                            // S6 (PT reads done)

    // ---- stage A2 (hi/lo, b128) into PT region ----
    {
        u32 hp[4], lp[4];
        #pragma unroll
        for (int k = 0; k < 4; ++k) splitpk(a2r[2*k], a2r[2*k+1], hp[k], lp[k]);
        *(uint4*)(ptAh + l5*AIMG_ST + c8*8) = make_uint4(hp[0], hp[1], hp[2], hp[3]);
        *(uint4*)(ptAl + l5*AIMG_ST + c8*8) = make_uint4(lp[0], lp[1], lp[2], lp[3]);
    }
    __syncthreads();                                            // S7

    gemm_q(ptAh, ptAl, wsu, ptQP, miQ, niA, lid, quad);         // Q2
    __syncthreads();                                            // S8

    f32x4 c20 = {0.f,0.f,0.f,0.f}, c21 = {0.f,0.f,0.f,0.f};
    gram_pt(ptQP, ptPT, 0, w, lid, quad);                       // branch-2 s-half 0
    __syncthreads();                                            // S9
    pv_ctx(ptPT, ptVH, 0, c20, c21, w, lid, quad);
    __syncthreads();                                            // S10 (WAR on PT)
    gram_pt(ptQP, ptPT, 1, w, lid, quad);                       // branch-2 s-half 1
    __syncthreads();                                            // S11
    pv_ctx(ptPT, ptVH, 1, c20, c21, w, lid, quad);

    // ---- epilogue: out[d=lid][t] = lrelu(ctx1)+lrelu(ctx2), float4 over r ----
    float* ob = out + ((size_t)N << 11) + lid*128;
    #pragma unroll
    for (int tj2 = 0; tj2 < 2; ++tj2) {
        f32x4 a = tj2 ? c11 : c10;
        f32x4 b = tj2 ? c21 : c20;
        float4 ov;
        ov.x = lrelu(a[0]) + lrelu(b[0]);
        ov.y = lrelu(a[1]) + lrelu(b[1]);
        ov.z = lrelu(a[2]) + lrelu(b[2]);
        ov.w = lrelu(a[3]) + lrelu(b[3]);
        *(float4*)(ob + (2*w + tj2)*16 + quad*4) = ov;
    }
}

extern "C" void kernel_launch(void* const* d_in, const int* in_sizes, int n_in,
                              void* d_out, int out_size, void* d_ws, size_t ws_size,
                              hipStream_t stream) {
    const float* z  = (const float*)d_in[0];
    const float* Wq = (const float*)d_in[1];
    const float* Wk = (const float*)d_in[2];
    float* out = (float*)d_out;
    u16* ws = (u16*)d_ws;
    hipLaunchKernelGGL(split_w_kernel, dim3(32), dim3(256), 0, stream, Wq, Wk, ws);
    hipLaunchKernelGGL(axial_attn_mfma, dim3(4096), dim3(256), 0, stream, z, ws, out);
}